// Round 5
// baseline (693.292 us; speedup 1.0000x reference)
//
#include <hip/hip_runtime.h>

#define N_NODES 50000
#define N_EDGES 800000
#define IN_DIM 128
#define OUT_DIM 64
#define ROWS 64            // rows per block in gemm
#define NB 782             // buckets of 64 nodes: ceil(50000/64)
#define BIN_CHUNK 4096     // edges per binning block
#define NBIN ((N_EDGES + BIN_CHUNK - 1) / BIN_CHUNK)   // 196

__device__ __forceinline__ unsigned short f2bf(float f) {
    unsigned u = __builtin_bit_cast(unsigned, f);
    u += 0x7FFF + ((u >> 16) & 1);          // round-to-nearest-even
    return (unsigned short)(u >> 16);
}
__device__ __forceinline__ float bf2f(unsigned short u) {
    unsigned x = ((unsigned)u) << 16;
    return __builtin_bit_cast(float, x);
}

// ---------------------------------------------------------------------------
// Kernel 1: h = x @ w, stored as bf16.  (f32 compute, bf16 store)
// 256 threads = 16 dim-groups x 16 row-groups; each thread 4 rows x 4 dims.
// ---------------------------------------------------------------------------
__global__ __launch_bounds__(256, 2) void gc_gemm(const float* __restrict__ x,
                                                  const float* __restrict__ w,
                                                  unsigned short* __restrict__ h16) {
    __shared__ float w_lds[IN_DIM * OUT_DIM];   // 32 KB
    __shared__ float x_lds[ROWS * IN_DIM];      // 32 KB (swizzled)

    const int tid = threadIdx.x;
    const int row0 = blockIdx.x * ROWS;

    const float4* w4 = reinterpret_cast<const float4*>(w);
    float4* wl4 = reinterpret_cast<float4*>(w_lds);
#pragma unroll
    for (int i = 0; i < 8; ++i) wl4[tid + i * 256] = w4[tid + i * 256];

    const float4* x4 = reinterpret_cast<const float4*>(x);
    float4* xl4 = reinterpret_cast<float4*>(x_lds);
#pragma unroll
    for (int i = 0; i < 8; ++i) {
        const int idx = tid + i * 256;
        const int r = idx >> 5;
        const int kc = idx & 31;
        const int g = row0 + r;
        float4 v = make_float4(0.f, 0.f, 0.f, 0.f);
        if (g < N_NODES) v = x4[(size_t)g * 32 + kc];
        xl4[r * 32 + (kc ^ (r & 3))] = v;
    }
    __syncthreads();

    const int tx = tid & 15;
    const int ty = tid >> 4;
    const int sw = ty & 3;

    float4 acc[4];
#pragma unroll
    for (int i = 0; i < 4; ++i) acc[i] = make_float4(0.f, 0.f, 0.f, 0.f);

    for (int kc = 0; kc < 32; ++kc) {
        float4 xv[4], wv[4];
#pragma unroll
        for (int i = 0; i < 4; ++i)
            xv[i] = xl4[(ty + 16 * i) * 32 + (kc ^ sw)];
#pragma unroll
        for (int j = 0; j < 4; ++j)
            wv[j] = wl4[(kc * 4 + j) * 16 + tx];
#pragma unroll
        for (int i = 0; i < 4; ++i) {
            acc[i].x = fmaf(xv[i].x, wv[0].x, acc[i].x);
            acc[i].y = fmaf(xv[i].x, wv[0].y, acc[i].y);
            acc[i].z = fmaf(xv[i].x, wv[0].z, acc[i].z);
            acc[i].w = fmaf(xv[i].x, wv[0].w, acc[i].w);
            acc[i].x = fmaf(xv[i].y, wv[1].x, acc[i].x);
            acc[i].y = fmaf(xv[i].y, wv[1].y, acc[i].y);
            acc[i].z = fmaf(xv[i].y, wv[1].z, acc[i].z);
            acc[i].w = fmaf(xv[i].y, wv[1].w, acc[i].w);
            acc[i].x = fmaf(xv[i].z, wv[2].x, acc[i].x);
            acc[i].y = fmaf(xv[i].z, wv[2].y, acc[i].y);
            acc[i].z = fmaf(xv[i].z, wv[2].z, acc[i].z);
            acc[i].w = fmaf(xv[i].z, wv[2].w, acc[i].w);
            acc[i].x = fmaf(xv[i].w, wv[3].x, acc[i].x);
            acc[i].y = fmaf(xv[i].w, wv[3].y, acc[i].y);
            acc[i].z = fmaf(xv[i].w, wv[3].z, acc[i].z);
            acc[i].w = fmaf(xv[i].w, wv[3].w, acc[i].w);
        }
    }

    ushort4* h4 = reinterpret_cast<ushort4*>(h16);
#pragma unroll
    for (int i = 0; i < 4; ++i) {
        const int r = row0 + ty + 16 * i;
        if (r < N_NODES) {
            ushort4 o;
            o.x = f2bf(acc[i].x);
            o.y = f2bf(acc[i].y);
            o.z = f2bf(acc[i].z);
            o.w = f2bf(acc[i].w);
            h4[(size_t)r * 16 + tx] = o;
        }
    }
}

// ---------------------------------------------------------------------------
// Bucket histogram (bucket = dst>>6). LDS-staged, then NB global atomics/block.
// bcnt pre-zeroed.
// ---------------------------------------------------------------------------
__global__ __launch_bounds__(512) void gc_bhist(const int* __restrict__ edst,
                                                int* __restrict__ bcnt) {
    __shared__ int lh[NB];
    const int t = threadIdx.x;
    for (int i = t; i < NB; i += 512) lh[i] = 0;
    __syncthreads();
    const int base = blockIdx.x * BIN_CHUNK;
#pragma unroll
    for (int k = 0; k < 8; ++k) {
        const int e = base + k * 512 + t;
        if (e < N_EDGES) atomicAdd(&lh[edst[e] >> 6], 1);
    }
    __syncthreads();
    for (int i = t; i < NB; i += 512) {
        const int c = lh[i];
        if (c) atomicAdd(&bcnt[i], c);
    }
}

// ---------------------------------------------------------------------------
// Exclusive scan of bcnt[NB] -> bstart (pristine starts) and bcur (cursors).
// Single block, 1024 threads.
// ---------------------------------------------------------------------------
__global__ __launch_bounds__(1024) void gc_bscan(const int* __restrict__ bcnt,
                                                 int* __restrict__ bstart,
                                                 int* __restrict__ bcur) {
    __shared__ int part[1024];
    const int t = threadIdx.x;
    const int v = (t < NB) ? bcnt[t] : 0;
    part[t] = v;
    __syncthreads();
#pragma unroll
    for (int off = 1; off < 1024; off <<= 1) {
        const int u = (t >= off) ? part[t - off] : 0;
        __syncthreads();
        part[t] += u;
        __syncthreads();
    }
    if (t < NB) {
        const int ex = part[t] - v;
        bstart[t] = ex;
        bcur[t] = ex;
    }
}

// ---------------------------------------------------------------------------
// Binning pass: stage 4096 edges in LDS grouped by bucket, flush each bucket
// group with one cursor-atomic + contiguous stores (full-line writes).
// Record: (dst<<16)|src  (both < 2^16), weight bits.
// ---------------------------------------------------------------------------
__global__ __launch_bounds__(512) void gc_bin(const int* __restrict__ esrc,
                                              const int* __restrict__ edst,
                                              const float* __restrict__ ew,
                                              int* __restrict__ bcur,
                                              int2* __restrict__ tmp) {
    __shared__ int2 stage[BIN_CHUNK];   // 32 KB
    __shared__ int lh[NB];
    __shared__ int lbase[NB];
    __shared__ int lcur[NB];
    __shared__ int part[512];

    const int t = threadIdx.x;
    const int base = blockIdx.x * BIN_CHUNK;

    for (int i = t; i < NB; i += 512) lh[i] = 0;
    __syncthreads();

    int2 rec[8];
    int bkt[8];
    bool val[8];
#pragma unroll
    for (int k = 0; k < 8; ++k) {
        const int e = base + k * 512 + t;
        val[k] = (e < N_EDGES);
        if (val[k]) {
            const int d = edst[e];
            rec[k] = make_int2((int)(((unsigned)d << 16) | (unsigned)esrc[e]),
                               __float_as_int(ew[e]));
            bkt[k] = d >> 6;
            atomicAdd(&lh[bkt[k]], 1);
        }
    }
    __syncthreads();

    // Exclusive scan of lh[782]: thread t<391 owns entries 2t, 2t+1.
    {
        int s = 0;
        if (t < 391) s = lh[2 * t] + lh[2 * t + 1];
        part[t] = s;
        __syncthreads();
#pragma unroll
        for (int off = 1; off < 512; off <<= 1) {
            const int u = (t >= off) ? part[t - off] : 0;
            __syncthreads();
            part[t] += u;
            __syncthreads();
        }
        if (t < 391) {
            const int pre = part[t] - s;
            lbase[2 * t] = pre;
            lcur[2 * t] = pre;
            lbase[2 * t + 1] = pre + lh[2 * t];
            lcur[2 * t + 1] = pre + lh[2 * t];
        }
    }
    __syncthreads();

#pragma unroll
    for (int k = 0; k < 8; ++k)
        if (val[k]) {
            const int p = atomicAdd(&lcur[bkt[k]], 1);
            stage[p] = rec[k];
        }
    __syncthreads();

    // Flush: wave wv handles buckets wv, wv+8, ...
    const int wv = t >> 6, ln = t & 63;
    for (int b = wv; b < NB; b += 8) {
        const int cnt = lh[b];
        if (!cnt) continue;
        int gbase;
        if (ln == 0) gbase = atomicAdd(&bcur[b], cnt);
        gbase = __builtin_amdgcn_readfirstlane(gbase);
        const int lb = lbase[b];
        for (int i = ln; i < cnt; i += 64) tmp[gbase + i] = stage[lb + i];
    }
}

// ---------------------------------------------------------------------------
// Fused aggregate: one block per 64-node bucket. 64x64 f32 tile in LDS;
// stream bucket edges, gather h row (bf16), LDS-atomic accumulate,
// then ReLU + store tile. Covers all nodes -> no memset/relu kernels.
// ---------------------------------------------------------------------------
__global__ __launch_bounds__(256) void gc_bagg(const unsigned short* __restrict__ h16,
                                               const int* __restrict__ bstart,
                                               const int* __restrict__ bcur,
                                               const int2* __restrict__ tmp,
                                               float* __restrict__ out) {
    __shared__ float tile[64 * 64];   // 16 KB
    const int t = threadIdx.x;
    const int b = blockIdx.x;

    float4* t4 = reinterpret_cast<float4*>(tile);
    for (int i = t; i < 1024; i += 256) t4[i] = make_float4(0.f, 0.f, 0.f, 0.f);
    __syncthreads();

    const int beg = bstart[b];
    const int end = bcur[b];        // == end after binning
    const int wv = t >> 6, ln = t & 63;

    // Split this bucket's edge range across the 4 waves.
    const int cnt = end - beg;
    const int wbeg = beg + (int)(((long long)cnt * wv) >> 2);
    const int wend = beg + (int)(((long long)cnt * (wv + 1)) >> 2);

    int j = wbeg;
    for (; j + 8 <= wend; j += 8) {
        unsigned pk[8];
        float wt[8];
#pragma unroll
        for (int k = 0; k < 8; ++k) {
            const int2 r = tmp[j + k];
            pk[k] = (unsigned)__builtin_amdgcn_readfirstlane(r.x);
            wt[k] = __int_as_float(__builtin_amdgcn_readfirstlane(r.y));
        }
        float v[8];
#pragma unroll
        for (int k = 0; k < 8; ++k) {
            const int src = (int)(pk[k] & 0xFFFFu);
            v[k] = bf2f(h16[(size_t)src * OUT_DIM + ln]);
        }
#pragma unroll
        for (int k = 0; k < 8; ++k) {
            const int row = (int)((pk[k] >> 16) & 63u);
            atomicAdd(&tile[row * 64 + ln], wt[k] * v[k]);
        }
    }
    for (; j < wend; ++j) {
        const int2 r = tmp[j];
        const unsigned p = (unsigned)__builtin_amdgcn_readfirstlane(r.x);
        const float wt = __int_as_float(__builtin_amdgcn_readfirstlane(r.y));
        const int src = (int)(p & 0xFFFFu);
        const int row = (int)((p >> 16) & 63u);
        atomicAdd(&tile[row * 64 + ln], wt * bf2f(h16[(size_t)src * OUT_DIM + ln]));
    }
    __syncthreads();

    // ReLU + store tile (64 rows x 16 float4).
    float4* o4 = reinterpret_cast<float4*>(out);
    const int node0 = b * 64;
    for (int i = t; i < 1024; i += 256) {
        const int r = i >> 4;
        const int g = node0 + r;
        if (g < N_NODES) {
            float4 vv = t4[i];
            vv.x = fmaxf(vv.x, 0.f);
            vv.y = fmaxf(vv.y, 0.f);
            vv.z = fmaxf(vv.z, 0.f);
            vv.w = fmaxf(vv.w, 0.f);
            o4[(size_t)g * 16 + (i & 15)] = vv;
        }
    }
}

extern "C" void kernel_launch(void* const* d_in, const int* in_sizes, int n_in,
                              void* d_out, int out_size, void* d_ws, size_t ws_size,
                              hipStream_t stream) {
    const float* x    = (const float*)d_in[0];
    const int*   esrc = (const int*)d_in[1];
    const int*   edst = (const int*)d_in[2];
    const float* ew   = (const float*)d_in[3];
    const float* w    = (const float*)d_in[4];
    float* out = (float*)d_out;

    // Workspace layout (~12.9 MB):
    unsigned short* h16 = (unsigned short*)d_ws;                  // 3.2M bf16 (6.4 MB)
    int*  bcnt   = (int*)(h16 + (size_t)N_NODES * OUT_DIM);       // NB ints
    int*  bstart = bcnt + 800;                                    // NB ints
    int*  bcur   = bstart + 800;                                  // NB ints
    int2* tmp    = (int2*)(bcur + 800 + 16);                      // 800,000 int2 (6.4 MB)

    // h = x @ w (bf16 store)
    gc_gemm<<<(N_NODES + ROWS - 1) / ROWS, 256, 0, stream>>>(x, w, h16);

    // Bucket counts -> starts/cursors -> binned edge records.
    hipMemsetAsync(bcnt, 0, NB * sizeof(int), stream);
    gc_bhist<<<NBIN, 512, 0, stream>>>(edst, bcnt);
    gc_bscan<<<1, 1024, 0, stream>>>(bcnt, bstart, bcur);
    gc_bin<<<NBIN, 512, 0, stream>>>(esrc, edst, ew, bcur, tmp);

    // Per-bucket fused gather-accumulate + ReLU.
    gc_bagg<<<NB, 256, 0, stream>>>(h16, bstart, bcur, tmp, out);
}

// Round 7
// 605.149 us; speedup vs baseline: 1.1457x; 1.1457x over previous
//
#include <hip/hip_runtime.h>

#define N_NODES 50000
#define N_EDGES 800000
#define IN_DIM 128
#define OUT_DIM 64
#define ROWS 64            // rows per block in gemm
#define NB 782             // buckets of 64 nodes: ceil(50000/64)
#define CHUNK 8192         // edges per count/bin block
#define NCH ((N_EDGES + CHUNK - 1) / CHUNK)    // 98
#define SCAN_N (NB * NCH)                      // 76,636
#define CPT 75             // scan elements per thread (1024*75 >= 76,636)

__device__ __forceinline__ unsigned short f2bf(float f) {
    unsigned u = __builtin_bit_cast(unsigned, f);
    u += 0x7FFF + ((u >> 16) & 1);          // round-to-nearest-even
    return (unsigned short)(u >> 16);
}

// ---------------------------------------------------------------------------
// Kernel 1: h = x @ w, stored as bf16.  (f32 compute, bf16 store)
// ---------------------------------------------------------------------------
__global__ __launch_bounds__(256, 2) void gc_gemm(const float* __restrict__ x,
                                                  const float* __restrict__ w,
                                                  unsigned short* __restrict__ h16) {
    __shared__ float w_lds[IN_DIM * OUT_DIM];   // 32 KB
    __shared__ float x_lds[ROWS * IN_DIM];      // 32 KB (swizzled)

    const int tid = threadIdx.x;
    const int row0 = blockIdx.x * ROWS;

    const float4* w4 = reinterpret_cast<const float4*>(w);
    float4* wl4 = reinterpret_cast<float4*>(w_lds);
#pragma unroll
    for (int i = 0; i < 8; ++i) wl4[tid + i * 256] = w4[tid + i * 256];

    const float4* x4 = reinterpret_cast<const float4*>(x);
    float4* xl4 = reinterpret_cast<float4*>(x_lds);
#pragma unroll
    for (int i = 0; i < 8; ++i) {
        const int idx = tid + i * 256;
        const int r = idx >> 5;
        const int kc = idx & 31;
        const int g = row0 + r;
        float4 v = make_float4(0.f, 0.f, 0.f, 0.f);
        if (g < N_NODES) v = x4[(size_t)g * 32 + kc];
        xl4[r * 32 + (kc ^ (r & 3))] = v;
    }
    __syncthreads();

    const int tx = tid & 15;
    const int ty = tid >> 4;
    const int sw = ty & 3;

    float4 acc[4];
#pragma unroll
    for (int i = 0; i < 4; ++i) acc[i] = make_float4(0.f, 0.f, 0.f, 0.f);

    for (int kc = 0; kc < 32; ++kc) {
        float4 xv[4], wv[4];
#pragma unroll
        for (int i = 0; i < 4; ++i)
            xv[i] = xl4[(ty + 16 * i) * 32 + (kc ^ sw)];
#pragma unroll
        for (int j = 0; j < 4; ++j)
            wv[j] = wl4[(kc * 4 + j) * 16 + tx];
#pragma unroll
        for (int i = 0; i < 4; ++i) {
            acc[i].x = fmaf(xv[i].x, wv[0].x, acc[i].x);
            acc[i].y = fmaf(xv[i].x, wv[0].y, acc[i].y);
            acc[i].z = fmaf(xv[i].x, wv[0].z, acc[i].z);
            acc[i].w = fmaf(xv[i].x, wv[0].w, acc[i].w);
            acc[i].x = fmaf(xv[i].y, wv[1].x, acc[i].x);
            acc[i].y = fmaf(xv[i].y, wv[1].y, acc[i].y);
            acc[i].z = fmaf(xv[i].y, wv[1].z, acc[i].z);
            acc[i].w = fmaf(xv[i].y, wv[1].w, acc[i].w);
            acc[i].x = fmaf(xv[i].z, wv[2].x, acc[i].x);
            acc[i].y = fmaf(xv[i].z, wv[2].y, acc[i].y);
            acc[i].z = fmaf(xv[i].z, wv[2].z, acc[i].z);
            acc[i].w = fmaf(xv[i].z, wv[2].w, acc[i].w);
            acc[i].x = fmaf(xv[i].w, wv[3].x, acc[i].x);
            acc[i].y = fmaf(xv[i].w, wv[3].y, acc[i].y);
            acc[i].z = fmaf(xv[i].w, wv[3].z, acc[i].z);
            acc[i].w = fmaf(xv[i].w, wv[3].w, acc[i].w);
        }
    }

    ushort4* h4 = reinterpret_cast<ushort4*>(h16);
#pragma unroll
    for (int i = 0; i < 4; ++i) {
        const int r = row0 + ty + 16 * i;
        if (r < N_NODES) {
            ushort4 o;
            o.x = f2bf(acc[i].x);
            o.y = f2bf(acc[i].y);
            o.z = f2bf(acc[i].z);
            o.w = f2bf(acc[i].w);
            h4[(size_t)r * 16 + tx] = o;
        }
    }
}

// ---------------------------------------------------------------------------
// Pass 1: per-chunk bucket counts -> cnt_mat[chunk][bucket] (coalesced write).
// ---------------------------------------------------------------------------
__global__ __launch_bounds__(512) void gc_count(const int* __restrict__ edst,
                                                int* __restrict__ cnt_mat) {
    __shared__ int lh[NB];
    const int t = threadIdx.x;
    for (int i = t; i < NB; i += 512) lh[i] = 0;
    __syncthreads();
    const int base = blockIdx.x * CHUNK;
#pragma unroll
    for (int k = 0; k < 16; ++k) {
        const int e = base + k * 512 + t;
        if (e < N_EDGES) atomicAdd(&lh[edst[e] >> 6], 1);
    }
    __syncthreads();
    for (int i = t; i < NB; i += 512) cnt_mat[blockIdx.x * NB + i] = lh[i];
}

// ---------------------------------------------------------------------------
// Pass 2: exclusive scan of cnt_mat in bucket-major order (i = b*NCH + blk)
// -> pos_mat[blk][b] (flush position for chunk blk, bucket b) and bstart[NB+1].
// Single block, 1024 threads, two read passes (no per-thread arrays).
// ---------------------------------------------------------------------------
__global__ __launch_bounds__(1024) void gc_scan(const int* __restrict__ cnt_mat,
                                                int* __restrict__ pos_mat,
                                                int* __restrict__ bstart) {
    __shared__ int part[1024];
    const int t = threadIdx.x;
    const int i0 = t * CPT;

    int sum = 0;
    for (int k = 0; k < CPT; ++k) {
        const int i = i0 + k;
        if (i < SCAN_N) sum += cnt_mat[(i % NCH) * NB + (i / NCH)];
    }
    part[t] = sum;
    __syncthreads();
#pragma unroll
    for (int off = 1; off < 1024; off <<= 1) {
        const int u = (t >= off) ? part[t - off] : 0;
        __syncthreads();
        part[t] += u;
        __syncthreads();
    }
    int run = part[t] - sum;   // exclusive prefix at i0
    for (int k = 0; k < CPT; ++k) {
        const int i = i0 + k;
        if (i < SCAN_N) {
            const int v = cnt_mat[(i % NCH) * NB + (i / NCH)];
            pos_mat[(i % NCH) * NB + (i / NCH)] = run;
            if (i % NCH == 0) bstart[i / NCH] = run;
            run += v;
        }
    }
    if (t == 0) bstart[NB] = N_EDGES;
}

// ---------------------------------------------------------------------------
// Pass 3: bin edges into bucket-grouped tmp[]. No global atomics — flush
// positions are deterministic from pos_mat. Record: (row_in_bucket<<16)|src.
// ---------------------------------------------------------------------------
__global__ __launch_bounds__(512) void gc_bin(const int* __restrict__ esrc,
                                              const int* __restrict__ edst,
                                              const float* __restrict__ ew,
                                              const int* __restrict__ pos_mat,
                                              int2* __restrict__ tmp) {
    __shared__ int2 stage[CHUNK];   // 64 KB
    __shared__ int lh[NB];
    __shared__ int lbase[NB];
    __shared__ int lcur[NB];
    __shared__ int part[512];

    const int t = threadIdx.x;
    const int base = blockIdx.x * CHUNK;

    for (int i = t; i < NB; i += 512) lh[i] = 0;
    __syncthreads();

#pragma unroll
    for (int k = 0; k < 16; ++k) {
        const int e = base + k * 512 + t;
        if (e < N_EDGES) atomicAdd(&lh[edst[e] >> 6], 1);
    }
    __syncthreads();

    // Local exclusive scan of lh[782]: thread t<391 owns entries 2t, 2t+1.
    {
        int s = 0;
        if (t < 391) s = lh[2 * t] + lh[2 * t + 1];
        part[t] = s;
        __syncthreads();
#pragma unroll
        for (int off = 1; off < 512; off <<= 1) {
            const int u = (t >= off) ? part[t - off] : 0;
            __syncthreads();
            part[t] += u;
            __syncthreads();
        }
        if (t < 391) {
            const int pre = part[t] - s;
            lbase[2 * t] = pre;
            lcur[2 * t] = pre;
            lbase[2 * t + 1] = pre + lh[2 * t];
            lcur[2 * t + 1] = pre + lh[2 * t];
        }
    }
    __syncthreads();

    // Stage edges grouped by bucket (LDS cursor atomics only).
#pragma unroll
    for (int k = 0; k < 16; ++k) {
        const int e = base + k * 512 + t;
        if (e < N_EDGES) {
            const int d = edst[e];
            const int p = atomicAdd(&lcur[d >> 6], 1);
            stage[p] = make_int2((int)(((unsigned)(d & 63) << 16) | (unsigned)esrc[e]),
                                 __float_as_int(ew[e]));
        }
    }
    __syncthreads();

    // Flush each bucket's group to its precomputed global slot (no atomics).
    const int wv = t >> 6, ln = t & 63;
    for (int b = wv; b < NB; b += 8) {
        const int cnt = lh[b];
        if (!cnt) continue;
        const int gbase = pos_mat[blockIdx.x * NB + b];
        const int lb = lbase[b];
        for (int i = ln; i < cnt; i += 64) tmp[gbase + i] = stage[lb + i];
    }
}

// ---------------------------------------------------------------------------
// Pass 4: fused aggregate + ReLU. One block per 64-node bucket.
// Lane l: edge slot k=l>>3, dim-group g=l&7 (dims g*8..g*8+7 via one int4).
// LDS tile stride 65 (65 mod 32 == 1) spreads atomic banks. No readfirstlane.
// ---------------------------------------------------------------------------
__global__ __launch_bounds__(512) void gc_bagg(const unsigned short* __restrict__ h16,
                                               const int* __restrict__ bstart,
                                               const int2* __restrict__ tmp,
                                               float* __restrict__ out) {
    __shared__ float tile[64 * 65];   // 16.6 KB
    const int t = threadIdx.x;
    const int b = blockIdx.x;

    for (int i = t; i < 64 * 65; i += 512) tile[i] = 0.f;
    __syncthreads();

    const int beg = bstart[b];
    const int end = bstart[b + 1];
    const int wv = t >> 6;
    const int ln = t & 63;
    const int k = ln >> 3;     // edge slot within group of 8
    const int g = ln & 7;      // dim group

    const int cnt = end - beg;
    const int wbeg = beg + (int)(((long long)cnt * wv) >> 3);
    const int wend = beg + (int)(((long long)cnt * (wv + 1)) >> 3);

#pragma unroll 2
    for (int j = wbeg; j < wend; j += 8) {
        const int jk = j + k;
        if (jk < wend) {
            const int2 r = tmp[jk];
            const float wt = __int_as_float(r.y);
            const int src = r.x & 0xFFFF;
            const int row = (r.x >> 16) & 63;
            const int4 p = *reinterpret_cast<const int4*>(
                h16 + (size_t)src * OUT_DIM + g * 8);
            float* tp = &tile[row * 65 + g * 8];
            atomicAdd(tp + 0, wt * __int_as_float((int)((unsigned)p.x << 16)));
            atomicAdd(tp + 1, wt * __int_as_float((int)(p.x & 0xFFFF0000)));
            atomicAdd(tp + 2, wt * __int_as_float((int)((unsigned)p.y << 16)));
            atomicAdd(tp + 3, wt * __int_as_float((int)(p.y & 0xFFFF0000)));
            atomicAdd(tp + 4, wt * __int_as_float((int)((unsigned)p.z << 16)));
            atomicAdd(tp + 5, wt * __int_as_float((int)(p.z & 0xFFFF0000)));
            atomicAdd(tp + 6, wt * __int_as_float((int)((unsigned)p.w << 16)));
            atomicAdd(tp + 7, wt * __int_as_float((int)(p.w & 0xFFFF0000)));
        }
    }
    __syncthreads();

    // ReLU + store (coalesced; covers every node -> no memset/relu kernels).
    const int node0 = b * 64;
    for (int i = t; i < 4096; i += 512) {
        const int r = i >> 6;
        const int c = i & 63;
        const int gn = node0 + r;
        if (gn < N_NODES)
            out[(size_t)gn * 64 + c] = fmaxf(tile[r * 65 + c], 0.f);
    }
}

extern "C" void kernel_launch(void* const* d_in, const int* in_sizes, int n_in,
                              void* d_out, int out_size, void* d_ws, size_t ws_size,
                              hipStream_t stream) {
    const float* x    = (const float*)d_in[0];
    const int*   esrc = (const int*)d_in[1];
    const int*   edst = (const int*)d_in[2];
    const float* ew   = (const float*)d_in[3];
    const float* w    = (const float*)d_in[4];
    float* out = (float*)d_out;

    // Workspace layout (~13.6 MB):
    unsigned short* h16 = (unsigned short*)d_ws;                 // 3.2M bf16 (6.4 MB)
    int*  cnt_mat = (int*)(h16 + (size_t)N_NODES * OUT_DIM);     // 76,636 ints
    int*  pos_mat = cnt_mat + 76800;                             // 76,636 ints
    int*  bstart  = pos_mat + 76800;                             // 783 ints
    int2* tmp     = (int2*)(bstart + 1024);                      // 800,000 int2 (6.4 MB)

    // h = x @ w (bf16 store)
    gc_gemm<<<(N_NODES + ROWS - 1) / ROWS, 256, 0, stream>>>(x, w, h16);

    // Deterministic bucket binning (no global atomics, no memsets).
    gc_count<<<NCH, 512, 0, stream>>>(edst, cnt_mat);
    gc_scan<<<1, 1024, 0, stream>>>(cnt_mat, pos_mat, bstart);
    gc_bin<<<NCH, 512, 0, stream>>>(esrc, edst, ew, pos_mat, tmp);

    // Per-bucket fused gather-accumulate + ReLU.
    gc_bagg<<<NB, 512, 0, stream>>>(h16, bstart, tmp, out);
}

// Round 8
// 327.213 us; speedup vs baseline: 2.1188x; 1.8494x over previous
//
#include <hip/hip_runtime.h>

#define N_NODES 50000
#define N_EDGES 800000
#define IN_DIM 128
#define OUT_DIM 64
#define ROWS 64            // rows per block in gemm
#define NB 782             // buckets of 64 nodes: ceil(50000/64)
#define CHUNK 8192         // edges per count/bin block
#define NCH ((N_EDGES + CHUNK - 1) / CHUNK)    // 98
#define SCAN_N (NB * NCH)                      // 76,636
#define CPT 75             // scan elements per thread (1024*75 >= 76,636)

__device__ __forceinline__ unsigned short f2bf(float f) {
    unsigned u = __builtin_bit_cast(unsigned, f);
    u += 0x7FFF + ((u >> 16) & 1);          // round-to-nearest-even
    return (unsigned short)(u >> 16);
}
__device__ __forceinline__ float bf2f(unsigned short u) {
    unsigned x = ((unsigned)u) << 16;
    return __builtin_bit_cast(float, x);
}

// ---------------------------------------------------------------------------
// Kernel 1: h = x @ w, stored as bf16.  (f32 compute, bf16 store)
// ---------------------------------------------------------------------------
__global__ __launch_bounds__(256, 2) void gc_gemm(const float* __restrict__ x,
                                                  const float* __restrict__ w,
                                                  unsigned short* __restrict__ h16) {
    __shared__ float w_lds[IN_DIM * OUT_DIM];   // 32 KB
    __shared__ float x_lds[ROWS * IN_DIM];      // 32 KB (swizzled)

    const int tid = threadIdx.x;
    const int row0 = blockIdx.x * ROWS;

    const float4* w4 = reinterpret_cast<const float4*>(w);
    float4* wl4 = reinterpret_cast<float4*>(w_lds);
#pragma unroll
    for (int i = 0; i < 8; ++i) wl4[tid + i * 256] = w4[tid + i * 256];

    const float4* x4 = reinterpret_cast<const float4*>(x);
    float4* xl4 = reinterpret_cast<float4*>(x_lds);
#pragma unroll
    for (int i = 0; i < 8; ++i) {
        const int idx = tid + i * 256;
        const int r = idx >> 5;
        const int kc = idx & 31;
        const int g = row0 + r;
        float4 v = make_float4(0.f, 0.f, 0.f, 0.f);
        if (g < N_NODES) v = x4[(size_t)g * 32 + kc];
        xl4[r * 32 + (kc ^ (r & 3))] = v;
    }
    __syncthreads();

    const int tx = tid & 15;
    const int ty = tid >> 4;
    const int sw = ty & 3;

    float4 acc[4];
#pragma unroll
    for (int i = 0; i < 4; ++i) acc[i] = make_float4(0.f, 0.f, 0.f, 0.f);

    for (int kc = 0; kc < 32; ++kc) {
        float4 xv[4], wv[4];
#pragma unroll
        for (int i = 0; i < 4; ++i)
            xv[i] = xl4[(ty + 16 * i) * 32 + (kc ^ sw)];
#pragma unroll
        for (int j = 0; j < 4; ++j)
            wv[j] = wl4[(kc * 4 + j) * 16 + tx];
#pragma unroll
        for (int i = 0; i < 4; ++i) {
            acc[i].x = fmaf(xv[i].x, wv[0].x, acc[i].x);
            acc[i].y = fmaf(xv[i].x, wv[0].y, acc[i].y);
            acc[i].z = fmaf(xv[i].x, wv[0].z, acc[i].z);
            acc[i].w = fmaf(xv[i].x, wv[0].w, acc[i].w);
            acc[i].x = fmaf(xv[i].y, wv[1].x, acc[i].x);
            acc[i].y = fmaf(xv[i].y, wv[1].y, acc[i].y);
            acc[i].z = fmaf(xv[i].y, wv[1].z, acc[i].z);
            acc[i].w = fmaf(xv[i].y, wv[1].w, acc[i].w);
            acc[i].x = fmaf(xv[i].z, wv[2].x, acc[i].x);
            acc[i].y = fmaf(xv[i].z, wv[2].y, acc[i].y);
            acc[i].z = fmaf(xv[i].z, wv[2].z, acc[i].z);
            acc[i].w = fmaf(xv[i].z, wv[2].w, acc[i].w);
            acc[i].x = fmaf(xv[i].w, wv[3].x, acc[i].x);
            acc[i].y = fmaf(xv[i].w, wv[3].y, acc[i].y);
            acc[i].z = fmaf(xv[i].w, wv[3].z, acc[i].z);
            acc[i].w = fmaf(xv[i].w, wv[3].w, acc[i].w);
        }
    }

    ushort4* h4 = reinterpret_cast<ushort4*>(h16);
#pragma unroll
    for (int i = 0; i < 4; ++i) {
        const int r = row0 + ty + 16 * i;
        if (r < N_NODES) {
            ushort4 o;
            o.x = f2bf(acc[i].x);
            o.y = f2bf(acc[i].y);
            o.z = f2bf(acc[i].z);
            o.w = f2bf(acc[i].w);
            h4[(size_t)r * 16 + tx] = o;
        }
    }
}

// ---------------------------------------------------------------------------
// Pass 1: per-chunk bucket counts -> cnt_mat[chunk][bucket] (coalesced write).
// ---------------------------------------------------------------------------
__global__ __launch_bounds__(512) void gc_count(const int* __restrict__ edst,
                                                int* __restrict__ cnt_mat) {
    __shared__ int lh[NB];
    const int t = threadIdx.x;
    for (int i = t; i < NB; i += 512) lh[i] = 0;
    __syncthreads();
    const int base = blockIdx.x * CHUNK;
#pragma unroll
    for (int k = 0; k < 16; ++k) {
        const int e = base + k * 512 + t;
        if (e < N_EDGES) atomicAdd(&lh[edst[e] >> 6], 1);
    }
    __syncthreads();
    for (int i = t; i < NB; i += 512) cnt_mat[blockIdx.x * NB + i] = lh[i];
}

// ---------------------------------------------------------------------------
// Pass 2: exclusive scan of cnt_mat in bucket-major order (i = b*NCH + blk)
// -> pos_mat[blk][b] (flush position for chunk blk, bucket b) and bstart[NB+1].
// ---------------------------------------------------------------------------
__global__ __launch_bounds__(1024) void gc_scan(const int* __restrict__ cnt_mat,
                                                int* __restrict__ pos_mat,
                                                int* __restrict__ bstart) {
    __shared__ int part[1024];
    const int t = threadIdx.x;
    const int i0 = t * CPT;

    int sum = 0;
    for (int k = 0; k < CPT; ++k) {
        const int i = i0 + k;
        if (i < SCAN_N) sum += cnt_mat[(i % NCH) * NB + (i / NCH)];
    }
    part[t] = sum;
    __syncthreads();
#pragma unroll
    for (int off = 1; off < 1024; off <<= 1) {
        const int u = (t >= off) ? part[t - off] : 0;
        __syncthreads();
        part[t] += u;
        __syncthreads();
    }
    int run = part[t] - sum;   // exclusive prefix at i0
    for (int k = 0; k < CPT; ++k) {
        const int i = i0 + k;
        if (i < SCAN_N) {
            const int v = cnt_mat[(i % NCH) * NB + (i / NCH)];
            pos_mat[(i % NCH) * NB + (i / NCH)] = run;
            if (i % NCH == 0) bstart[i / NCH] = run;
            run += v;
        }
    }
    if (t == 0) bstart[NB] = N_EDGES;
}

// ---------------------------------------------------------------------------
// Pass 3: bin edges into bucket-grouped tmp[]. No global atomics — flush
// positions are deterministic from pos_mat. Record: (row_in_bucket<<16)|src.
// ---------------------------------------------------------------------------
__global__ __launch_bounds__(512) void gc_bin(const int* __restrict__ esrc,
                                              const int* __restrict__ edst,
                                              const float* __restrict__ ew,
                                              const int* __restrict__ pos_mat,
                                              int2* __restrict__ tmp) {
    __shared__ int2 stage[CHUNK];   // 64 KB
    __shared__ int lh[NB];
    __shared__ int lbase[NB];
    __shared__ int lcur[NB];
    __shared__ int part[512];

    const int t = threadIdx.x;
    const int base = blockIdx.x * CHUNK;

    for (int i = t; i < NB; i += 512) lh[i] = 0;
    __syncthreads();

#pragma unroll
    for (int k = 0; k < 16; ++k) {
        const int e = base + k * 512 + t;
        if (e < N_EDGES) atomicAdd(&lh[edst[e] >> 6], 1);
    }
    __syncthreads();

    // Local exclusive scan of lh[782]: thread t<391 owns entries 2t, 2t+1.
    {
        int s = 0;
        if (t < 391) s = lh[2 * t] + lh[2 * t + 1];
        part[t] = s;
        __syncthreads();
#pragma unroll
        for (int off = 1; off < 512; off <<= 1) {
            const int u = (t >= off) ? part[t - off] : 0;
            __syncthreads();
            part[t] += u;
            __syncthreads();
        }
        if (t < 391) {
            const int pre = part[t] - s;
            lbase[2 * t] = pre;
            lcur[2 * t] = pre;
            lbase[2 * t + 1] = pre + lh[2 * t];
            lcur[2 * t + 1] = pre + lh[2 * t];
        }
    }
    __syncthreads();

    // Stage edges grouped by bucket (LDS cursor atomics only).
#pragma unroll
    for (int k = 0; k < 16; ++k) {
        const int e = base + k * 512 + t;
        if (e < N_EDGES) {
            const int d = edst[e];
            const int p = atomicAdd(&lcur[d >> 6], 1);
            stage[p] = make_int2((int)(((unsigned)(d & 63) << 16) | (unsigned)esrc[e]),
                                 __float_as_int(ew[e]));
        }
    }
    __syncthreads();

    // Flush each bucket's group to its precomputed global slot (no atomics).
    const int wv = t >> 6, ln = t & 63;
    for (int b = wv; b < NB; b += 8) {
        const int cnt = lh[b];
        if (!cnt) continue;
        const int gbase = pos_mat[blockIdx.x * NB + b];
        const int lb = lbase[b];
        for (int i = ln; i < cnt; i += 64) tmp[gbase + i] = stage[lb + i];
    }
}

// ---------------------------------------------------------------------------
// Pass 4: fused aggregate + ReLU. One block (256 thr = 4 waves) per bucket.
// Each wave owns a PRIVATE 64x64 f32 tile (no atomics): lane = dim, one edge
// per wave-instruction -> all 64 lanes hit distinct addresses; same-wave DS
// ordering makes read-fma-write over repeating rows race-free. Global loads
// batched 8-deep for latency hiding.
// ---------------------------------------------------------------------------
__global__ __launch_bounds__(256) void gc_bagg(const unsigned short* __restrict__ h16,
                                               const int* __restrict__ bstart,
                                               const int2* __restrict__ tmp,
                                               float* __restrict__ out) {
    __shared__ float tiles[4 * 64 * 64];   // 64 KB: one private tile per wave
    const int t = threadIdx.x;
    const int b = blockIdx.x;
    const int wv = t >> 6;
    const int ln = t & 63;

    for (int i = t; i < 4 * 4096; i += 256) tiles[i] = 0.f;
    __syncthreads();

    float* tile = &tiles[wv * 4096];

    const int beg = bstart[b];
    const int end = bstart[b + 1];
    const int cnt = end - beg;
    const int wbeg = beg + ((cnt * wv) >> 2);
    const int wend = beg + ((cnt * (wv + 1)) >> 2);
    const int wcnt = wend - wbeg;
    const int nfull = wcnt & ~7;

    for (int jj = 0; jj < nfull; jj += 8) {
        const int j = wbeg + jj;
        int2 rec[8];
#pragma unroll
        for (int i = 0; i < 8; ++i) rec[i] = tmp[j + i];      // uniform (1 line)
        float hv[8];
#pragma unroll
        for (int i = 0; i < 8; ++i) {                          // 8 gathers in flight
            const int src = rec[i].x & 0xFFFF;
            hv[i] = bf2f(h16[(size_t)src * OUT_DIM + ln]);
        }
#pragma unroll
        for (int i = 0; i < 8; ++i) {                          // ordered RMW chain
            const int row = (rec[i].x >> 16) & 63;
            tile[row * 64 + ln] += __int_as_float(rec[i].y) * hv[i];
        }
    }
    for (int jj = nfull; jj < wcnt; ++jj) {
        const int2 r = tmp[wbeg + jj];
        const int src = r.x & 0xFFFF;
        const int row = (r.x >> 16) & 63;
        tile[row * 64 + ln] += __int_as_float(r.y) * bf2f(h16[(size_t)src * OUT_DIM + ln]);
    }
    __syncthreads();

    // Merge 4 private tiles + ReLU + coalesced float4 store.
    const int node0 = b * 64;
    float4* o4 = reinterpret_cast<float4*>(out);
    const float4* t4 = reinterpret_cast<const float4*>(tiles);
    for (int i = t; i < 1024; i += 256) {     // 1024 float4 per tile
        const float4 a = t4[i];
        const float4 b2 = t4[1024 + i];
        const float4 c = t4[2048 + i];
        const float4 d = t4[3072 + i];
        float4 s;
        s.x = fmaxf(a.x + b2.x + c.x + d.x, 0.f);
        s.y = fmaxf(a.y + b2.y + c.y + d.y, 0.f);
        s.z = fmaxf(a.z + b2.z + c.z + d.z, 0.f);
        s.w = fmaxf(a.w + b2.w + c.w + d.w, 0.f);
        const int r = i >> 4;
        const int gn = node0 + r;
        if (gn < N_NODES) o4[(size_t)gn * 16 + (i & 15)] = s;
    }
}

extern "C" void kernel_launch(void* const* d_in, const int* in_sizes, int n_in,
                              void* d_out, int out_size, void* d_ws, size_t ws_size,
                              hipStream_t stream) {
    const float* x    = (const float*)d_in[0];
    const int*   esrc = (const int*)d_in[1];
    const int*   edst = (const int*)d_in[2];
    const float* ew   = (const float*)d_in[3];
    const float* w    = (const float*)d_in[4];
    float* out = (float*)d_out;

    // Workspace layout (~13.6 MB):
    unsigned short* h16 = (unsigned short*)d_ws;                 // 3.2M bf16 (6.4 MB)
    int*  cnt_mat = (int*)(h16 + (size_t)N_NODES * OUT_DIM);     // 76,636 ints
    int*  pos_mat = cnt_mat + 76800;                             // 76,636 ints
    int*  bstart  = pos_mat + 76800;                             // 783 ints
    int2* tmp     = (int2*)(bstart + 1024);                      // 800,000 int2 (6.4 MB)

    // h = x @ w (bf16 store)
    gc_gemm<<<(N_NODES + ROWS - 1) / ROWS, 256, 0, stream>>>(x, w, h16);

    // Deterministic bucket binning (no global atomics, no memsets).
    gc_count<<<NCH, 512, 0, stream>>>(edst, cnt_mat);
    gc_scan<<<1, 1024, 0, stream>>>(cnt_mat, pos_mat, bstart);
    gc_bin<<<NCH, 512, 0, stream>>>(esrc, edst, ew, pos_mat, tmp);

    // Per-bucket fused gather-accumulate + ReLU (no atomics).
    gc_bagg<<<NB, 256, 0, stream>>>(h16, bstart, tmp, out);
}

// Round 9
// 219.732 us; speedup vs baseline: 3.1552x; 1.4891x over previous
//
#include <hip/hip_runtime.h>

#define N_NODES 50000
#define N_EDGES 800000
#define IN_DIM 128
#define OUT_DIM 64
#define ROWS 64            // rows per block in gemm
#define NB 782             // buckets of 64 nodes: ceil(50000/64)
#define CHUNK 8192         // edges per count/bin block
#define NCH ((N_EDGES + CHUNK - 1) / CHUNK)    // 98
#define SCAN_N (NB * NCH)                      // 76,636 (bucket-major, contiguous)
#define SCAN_BLK 512
#define NSC ((SCAN_N + SCAN_BLK - 1) / SCAN_BLK)   // 150

__device__ __forceinline__ unsigned short f2bf(float f) {
    unsigned u = __builtin_bit_cast(unsigned, f);
    u += 0x7FFF + ((u >> 16) & 1);          // round-to-nearest-even
    return (unsigned short)(u >> 16);
}
__device__ __forceinline__ float bf2f(unsigned short u) {
    unsigned x = ((unsigned)u) << 16;
    return __builtin_bit_cast(float, x);
}

// ---------------------------------------------------------------------------
// Kernel 1: h = x @ w, stored as bf16.  (f32 compute, bf16 store)
// ---------------------------------------------------------------------------
__global__ __launch_bounds__(256, 2) void gc_gemm(const float* __restrict__ x,
                                                  const float* __restrict__ w,
                                                  unsigned short* __restrict__ h16) {
    __shared__ float w_lds[IN_DIM * OUT_DIM];   // 32 KB
    __shared__ float x_lds[ROWS * IN_DIM];      // 32 KB (swizzled)

    const int tid = threadIdx.x;
    const int row0 = blockIdx.x * ROWS;

    const float4* w4 = reinterpret_cast<const float4*>(w);
    float4* wl4 = reinterpret_cast<float4*>(w_lds);
#pragma unroll
    for (int i = 0; i < 8; ++i) wl4[tid + i * 256] = w4[tid + i * 256];

    const float4* x4 = reinterpret_cast<const float4*>(x);
    float4* xl4 = reinterpret_cast<float4*>(x_lds);
#pragma unroll
    for (int i = 0; i < 8; ++i) {
        const int idx = tid + i * 256;
        const int r = idx >> 5;
        const int kc = idx & 31;
        const int g = row0 + r;
        float4 v = make_float4(0.f, 0.f, 0.f, 0.f);
        if (g < N_NODES) v = x4[(size_t)g * 32 + kc];
        xl4[r * 32 + (kc ^ (r & 3))] = v;
    }
    __syncthreads();

    const int tx = tid & 15;
    const int ty = tid >> 4;
    const int sw = ty & 3;

    float4 acc[4];
#pragma unroll
    for (int i = 0; i < 4; ++i) acc[i] = make_float4(0.f, 0.f, 0.f, 0.f);

    for (int kc = 0; kc < 32; ++kc) {
        float4 xv[4], wv[4];
#pragma unroll
        for (int i = 0; i < 4; ++i)
            xv[i] = xl4[(ty + 16 * i) * 32 + (kc ^ sw)];
#pragma unroll
        for (int j = 0; j < 4; ++j)
            wv[j] = wl4[(kc * 4 + j) * 16 + tx];
#pragma unroll
        for (int i = 0; i < 4; ++i) {
            acc[i].x = fmaf(xv[i].x, wv[0].x, acc[i].x);
            acc[i].y = fmaf(xv[i].x, wv[0].y, acc[i].y);
            acc[i].z = fmaf(xv[i].x, wv[0].z, acc[i].z);
            acc[i].w = fmaf(xv[i].x, wv[0].w, acc[i].w);
            acc[i].x = fmaf(xv[i].y, wv[1].x, acc[i].x);
            acc[i].y = fmaf(xv[i].y, wv[1].y, acc[i].y);
            acc[i].z = fmaf(xv[i].y, wv[1].z, acc[i].z);
            acc[i].w = fmaf(xv[i].y, wv[1].w, acc[i].w);
            acc[i].x = fmaf(xv[i].z, wv[2].x, acc[i].x);
            acc[i].y = fmaf(xv[i].z, wv[2].y, acc[i].y);
            acc[i].z = fmaf(xv[i].z, wv[2].z, acc[i].z);
            acc[i].w = fmaf(xv[i].z, wv[2].w, acc[i].w);
            acc[i].x = fmaf(xv[i].w, wv[3].x, acc[i].x);
            acc[i].y = fmaf(xv[i].w, wv[3].y, acc[i].y);
            acc[i].z = fmaf(xv[i].w, wv[3].z, acc[i].z);
            acc[i].w = fmaf(xv[i].w, wv[3].w, acc[i].w);
        }
    }

    ushort4* h4 = reinterpret_cast<ushort4*>(h16);
#pragma unroll
    for (int i = 0; i < 4; ++i) {
        const int r = row0 + ty + 16 * i;
        if (r < N_NODES) {
            ushort4 o;
            o.x = f2bf(acc[i].x);
            o.y = f2bf(acc[i].y);
            o.z = f2bf(acc[i].z);
            o.w = f2bf(acc[i].w);
            h4[(size_t)r * 16 + tx] = o;
        }
    }
}

// ---------------------------------------------------------------------------
// Pass 1: per-chunk bucket counts, written TRANSPOSED: cntT[b*NCH + blk].
// Scattered 4B writes (76k total) so the scan can read contiguously.
// ---------------------------------------------------------------------------
__global__ __launch_bounds__(512) void gc_count(const int* __restrict__ edst,
                                                int* __restrict__ cntT) {
    __shared__ int lh[NB];
    const int t = threadIdx.x;
    for (int i = t; i < NB; i += 512) lh[i] = 0;
    __syncthreads();
    const int base = blockIdx.x * CHUNK;
#pragma unroll
    for (int k = 0; k < 16; ++k) {
        const int e = base + k * 512 + t;
        if (e < N_EDGES) atomicAdd(&lh[edst[e] >> 6], 1);
    }
    __syncthreads();
    for (int i = t; i < NB; i += 512) cntT[i * NCH + blockIdx.x] = lh[i];
}

// ---------------------------------------------------------------------------
// Parallel exclusive scan of cntT[SCAN_N] (contiguous, bucket-major), 3 passes.
// In-place: cntT becomes posT. posT[b*NCH+blk] = flush base for (chunk blk,
// bucket b); posT[b*NCH] = bucket b start.
// ---------------------------------------------------------------------------
__global__ __launch_bounds__(256) void gc_scan1(const int* __restrict__ a,
                                                int* __restrict__ bsum) {
    __shared__ int red[256];
    const int t = threadIdx.x;
    const int i0 = blockIdx.x * SCAN_BLK + t * 2;
    int v = 0;
    if (i0 < SCAN_N) v += a[i0];
    if (i0 + 1 < SCAN_N) v += a[i0 + 1];
    red[t] = v;
    __syncthreads();
#pragma unroll
    for (int s = 128; s > 0; s >>= 1) {
        if (t < s) red[t] += red[t + s];
        __syncthreads();
    }
    if (t == 0) bsum[blockIdx.x] = red[0];
}

__global__ __launch_bounds__(256) void gc_scan2(int* __restrict__ bsum) {
    __shared__ int part[256];
    const int t = threadIdx.x;
    const int v = (t < NSC) ? bsum[t] : 0;
    part[t] = v;
    __syncthreads();
#pragma unroll
    for (int off = 1; off < 256; off <<= 1) {
        const int u = (t >= off) ? part[t - off] : 0;
        __syncthreads();
        part[t] += u;
        __syncthreads();
    }
    if (t < NSC) bsum[t] = part[t] - v;   // exclusive prefix of block sums
}

__global__ __launch_bounds__(256) void gc_scan3(int* __restrict__ a,
                                                const int* __restrict__ bsum) {
    __shared__ int part[256];
    const int t = threadIdx.x;
    const int i0 = blockIdx.x * SCAN_BLK + t * 2;
    const int v0 = (i0 < SCAN_N) ? a[i0] : 0;
    const int v1 = (i0 + 1 < SCAN_N) ? a[i0 + 1] : 0;
    const int s = v0 + v1;
    part[t] = s;
    __syncthreads();
#pragma unroll
    for (int off = 1; off < 256; off <<= 1) {
        const int u = (t >= off) ? part[t - off] : 0;
        __syncthreads();
        part[t] += u;
        __syncthreads();
    }
    const int pre = bsum[blockIdx.x] + part[t] - s;
    if (i0 < SCAN_N) a[i0] = pre;
    if (i0 + 1 < SCAN_N) a[i0 + 1] = pre + v0;
}

// ---------------------------------------------------------------------------
// Pass 3: bin edges into bucket-grouped tmp[]. No global atomics — flush
// positions are deterministic from posT. Record: (row_in_bucket<<16)|src.
// ---------------------------------------------------------------------------
__global__ __launch_bounds__(512) void gc_bin(const int* __restrict__ esrc,
                                              const int* __restrict__ edst,
                                              const float* __restrict__ ew,
                                              const int* __restrict__ posT,
                                              int2* __restrict__ tmp) {
    __shared__ int2 stage[CHUNK];   // 64 KB
    __shared__ int lh[NB];
    __shared__ int lbase[NB];
    __shared__ int lcur[NB];
    __shared__ int part[512];

    const int t = threadIdx.x;
    const int base = blockIdx.x * CHUNK;

    for (int i = t; i < NB; i += 512) lh[i] = 0;
    __syncthreads();

#pragma unroll
    for (int k = 0; k < 16; ++k) {
        const int e = base + k * 512 + t;
        if (e < N_EDGES) atomicAdd(&lh[edst[e] >> 6], 1);
    }
    __syncthreads();

    // Local exclusive scan of lh[782]: thread t<391 owns entries 2t, 2t+1.
    {
        int s = 0;
        if (t < 391) s = lh[2 * t] + lh[2 * t + 1];
        part[t] = s;
        __syncthreads();
#pragma unroll
        for (int off = 1; off < 512; off <<= 1) {
            const int u = (t >= off) ? part[t - off] : 0;
            __syncthreads();
            part[t] += u;
            __syncthreads();
        }
        if (t < 391) {
            const int pre = part[t] - s;
            lbase[2 * t] = pre;
            lcur[2 * t] = pre;
            lbase[2 * t + 1] = pre + lh[2 * t];
            lcur[2 * t + 1] = pre + lh[2 * t];
        }
    }
    __syncthreads();

    // Stage edges grouped by bucket (LDS cursor atomics only).
#pragma unroll
    for (int k = 0; k < 16; ++k) {
        const int e = base + k * 512 + t;
        if (e < N_EDGES) {
            const int d = edst[e];
            const int p = atomicAdd(&lcur[d >> 6], 1);
            stage[p] = make_int2((int)(((unsigned)(d & 63) << 16) | (unsigned)esrc[e]),
                                 __float_as_int(ew[e]));
        }
    }
    __syncthreads();

    // Flush each bucket's group to its precomputed global slot (no atomics).
    const int wv = t >> 6, ln = t & 63;
    for (int b = wv; b < NB; b += 8) {
        const int cnt = lh[b];
        if (!cnt) continue;
        const int gbase = posT[b * NCH + blockIdx.x];
        const int lb = lbase[b];
        for (int i = ln; i < cnt; i += 64) tmp[gbase + i] = stage[lb + i];
    }
}

// ---------------------------------------------------------------------------
// Pass 4: fused aggregate + ReLU. One block (256 thr = 4 waves) per bucket.
// Each wave owns a PRIVATE 64x64 f32 tile (no atomics); 8-deep gather batch.
// Bucket bounds come straight from posT[b*NCH].
// ---------------------------------------------------------------------------
__global__ __launch_bounds__(256) void gc_bagg(const unsigned short* __restrict__ h16,
                                               const int* __restrict__ posT,
                                               const int2* __restrict__ tmp,
                                               float* __restrict__ out) {
    __shared__ float tiles[4 * 64 * 64];   // 64 KB: one private tile per wave
    const int t = threadIdx.x;
    const int b = blockIdx.x;
    const int wv = t >> 6;
    const int ln = t & 63;

    for (int i = t; i < 4 * 4096; i += 256) tiles[i] = 0.f;
    __syncthreads();

    float* tile = &tiles[wv * 4096];

    const int beg = posT[b * NCH];
    const int end = (b + 1 < NB) ? posT[(b + 1) * NCH] : N_EDGES;
    const int cnt = end - beg;
    const int wbeg = beg + ((cnt * wv) >> 2);
    const int wend = beg + ((cnt * (wv + 1)) >> 2);
    const int wcnt = wend - wbeg;
    const int nfull = wcnt & ~7;

    for (int jj = 0; jj < nfull; jj += 8) {
        const int j = wbeg + jj;
        int2 rec[8];
#pragma unroll
        for (int i = 0; i < 8; ++i) rec[i] = tmp[j + i];      // uniform (1 line)
        float hv[8];
#pragma unroll
        for (int i = 0; i < 8; ++i) {                          // 8 gathers in flight
            const int src = rec[i].x & 0xFFFF;
            hv[i] = bf2f(h16[(size_t)src * OUT_DIM + ln]);
        }
#pragma unroll
        for (int i = 0; i < 8; ++i) {                          // ordered RMW chain
            const int row = (rec[i].x >> 16) & 63;
            tile[row * 64 + ln] += __int_as_float(rec[i].y) * hv[i];
        }
    }
    for (int jj = nfull; jj < wcnt; ++jj) {
        const int2 r = tmp[wbeg + jj];
        const int src = r.x & 0xFFFF;
        const int row = (r.x >> 16) & 63;
        tile[row * 64 + ln] += __int_as_float(r.y) * bf2f(h16[(size_t)src * OUT_DIM + ln]);
    }
    __syncthreads();

    // Merge 4 private tiles + ReLU + coalesced float4 store.
    const int node0 = b * 64;
    float4* o4 = reinterpret_cast<float4*>(out);
    const float4* t4 = reinterpret_cast<const float4*>(tiles);
    for (int i = t; i < 1024; i += 256) {     // 1024 float4 per tile
        const float4 a = t4[i];
        const float4 b2 = t4[1024 + i];
        const float4 c = t4[2048 + i];
        const float4 d = t4[3072 + i];
        float4 s;
        s.x = fmaxf(a.x + b2.x + c.x + d.x, 0.f);
        s.y = fmaxf(a.y + b2.y + c.y + d.y, 0.f);
        s.z = fmaxf(a.z + b2.z + c.z + d.z, 0.f);
        s.w = fmaxf(a.w + b2.w + c.w + d.w, 0.f);
        const int r = i >> 4;
        const int gn = node0 + r;
        if (gn < N_NODES) o4[(size_t)gn * 16 + (i & 15)] = s;
    }
}

extern "C" void kernel_launch(void* const* d_in, const int* in_sizes, int n_in,
                              void* d_out, int out_size, void* d_ws, size_t ws_size,
                              hipStream_t stream) {
    const float* x    = (const float*)d_in[0];
    const int*   esrc = (const int*)d_in[1];
    const int*   edst = (const int*)d_in[2];
    const float* ew   = (const float*)d_in[3];
    const float* w    = (const float*)d_in[4];
    float* out = (float*)d_out;

    // Workspace layout (~13.2 MB):
    unsigned short* h16 = (unsigned short*)d_ws;                 // 3.2M bf16 (6.4 MB)
    int*  cntT = (int*)(h16 + (size_t)N_NODES * OUT_DIM);        // 76,636 ints (-> posT)
    int*  bsum = cntT + 76800;                                   // 150 ints
    int2* tmp  = (int2*)(bsum + 256);                            // 800,000 int2 (6.4 MB)

    // h = x @ w (bf16 store)
    gc_gemm<<<(N_NODES + ROWS - 1) / ROWS, 256, 0, stream>>>(x, w, h16);

    // Deterministic bucket binning (no global atomics, no memsets).
    gc_count<<<NCH, 512, 0, stream>>>(edst, cntT);
    gc_scan1<<<NSC, 256, 0, stream>>>(cntT, bsum);
    gc_scan2<<<1, 256, 0, stream>>>(bsum);
    gc_scan3<<<NSC, 256, 0, stream>>>(cntT, bsum);   // cntT -> posT in place
    gc_bin<<<NCH, 512, 0, stream>>>(esrc, edst, ew, cntT, tmp);

    // Per-bucket fused gather-accumulate + ReLU (no atomics).
    gc_bagg<<<NB, 256, 0, stream>>>(h16, cntT, tmp, out);
}